// Round 2
// baseline (325.935 us; speedup 1.0000x reference)
//
#include <hip/hip_runtime.h>
#include <math.h>

#define BB 8
#define SS 2048
#define SSG 2050          // SS + 2 guard rows per batch for conv halo
#define DDIM 512
#define KC 1536
#define EPSV 1e-6f
#define SCALE 0.044194173824159216f   // 1/sqrt(512)

typedef unsigned short ushort_t;
using short8 = __attribute__((ext_vector_type(8))) short;
using f32x4  = __attribute__((ext_vector_type(4))) float;

__device__ inline unsigned short f2bf(float f) {
    union { float f; unsigned int u; } v; v.f = f;
    unsigned int r = v.u + 0x7FFFu + ((v.u >> 16) & 1u);   // RNE
    return (unsigned short)(r >> 16);
}
__device__ inline unsigned int packbf(float a, float b) {
    return (unsigned int)f2bf(a) | ((unsigned int)f2bf(b) << 16);
}
__device__ inline float bf2f(unsigned short s) {
    union { unsigned int u; float f; } v; v.u = ((unsigned int)s) << 16; return v.f;
}

// async global->LDS, 16B/lane; LDS dest is wave-uniform base + lane*16 (linear).
__device__ inline void gload16(const ushort_t* g, ushort_t* l) {
    __builtin_amdgcn_global_load_lds(
        (__attribute__((address_space(1))) const void*)g,
        (__attribute__((address_space(3))) void*)l, 16, 0, 0);
}

// bank swizzle for 64B (32-el) LDS rows: chunk c (0..3) of row r stored at c ^ g(r).
// g spreads each aligned 8-lane read beat across all 32 banks.
__device__ inline int gsw(int r) { return (r ^ (r >> 2)) & 3; }

// ---- pipeline sync macros (counted vmcnt, raw barriers, rule-18 fences) ----
#define PIPE_HEAD(N) do { \
    asm volatile("s_waitcnt vmcnt(" #N ")" ::: "memory"); \
    __builtin_amdgcn_sched_barrier(0); \
    __builtin_amdgcn_s_barrier(); \
    asm volatile("" ::: "memory"); \
    __builtin_amdgcn_sched_barrier(0); } while (0)

#define PIPE_TAIL() do { \
    asm volatile("s_waitcnt lgkmcnt(0)" ::: "memory"); \
    __builtin_amdgcn_sched_barrier(0); \
    __builtin_amdgcn_s_barrier(); \
    asm volatile("" ::: "memory"); \
    __builtin_amdgcn_sched_barrier(0); } while (0)

#define PIPE_HEAD_SEL(ti, NT) do { \
    if ((ti) < (NT) - 3)       PIPE_HEAD(9); \
    else if ((ti) == (NT) - 3) PIPE_HEAD(6); \
    else if ((ti) == (NT) - 2) PIPE_HEAD(3); \
    else                       PIPE_HEAD(0); } while (0)

#define MFMA16() do { \
    __builtin_amdgcn_s_setprio(1); \
    _Pragma("unroll") \
    for (int nt = 0; nt < 4; nt++) { \
        _Pragma("unroll") \
        for (int mt = 0; mt < 4; mt++) \
            acc[mt][nt] = __builtin_amdgcn_mfma_f32_16x16x32_bf16(av[mt], bv[nt], acc[mt][nt], 0, 0, 0); \
    } \
    __builtin_amdgcn_s_setprio(0); } while (0)

// ---------- kx: x fp32 -> bf16 (guarded layout), plus xsum[b][d] = sum_s x ----------
__global__ __launch_bounds__(256) void kx_cast(const float* __restrict__ x,
                                               ushort_t* __restrict__ xbf,
                                               float* __restrict__ xsum)
{
    const int t = threadIdx.x;
    const int b = blockIdx.y;
    const int r0 = blockIdx.x * 16;
    const int c0 = 2 * t;
    if (blockIdx.x == 0) {   // zero guard rows (row -1 and row SS of this batch)
        *reinterpret_cast<unsigned int*>(&xbf[((size_t)b * SSG) * DDIM + c0]) = 0u;
        *reinterpret_cast<unsigned int*>(&xbf[((size_t)b * SSG + SS + 1) * DDIM + c0]) = 0u;
    }
    float s0 = 0.f, s1 = 0.f;
    for (int r = 0; r < 16; r++) {
        size_t srow = (size_t)b * SS + r0 + r;
        size_t drow = (size_t)b * SSG + 1 + r0 + r;
        float2 v = *reinterpret_cast<const float2*>(&x[srow * DDIM + c0]);
        s0 += v.x; s1 += v.y;
        *reinterpret_cast<unsigned int*>(&xbf[drow * DDIM + c0]) = packbf(v.x, v.y);
    }
    atomicAdd(&xsum[b * DDIM + c0], s0);
    atomicAdd(&xsum[b * DDIM + c0 + 1], s1);
}

// ---------- k0: weights -> bf16 ----------
__global__ __launch_bounds__(256) void k0_prep(
    const float* __restrict__ conv_w, const float* __restrict__ Wq,
    const float* __restrict__ Wk, const float* __restrict__ Wv,
    ushort_t* __restrict__ wcat, ushort_t* __restrict__ wqkv)
{
    int idx = blockIdx.x * 256 + threadIdx.x;   // < 512*1536
    {
        int o = idx / KC, kk = idx - o * KC;
        int t = kk >> 9, i = kk & 511;
        wcat[idx] = f2bf(conv_w[(size_t)o * KC + i * 3 + t]);
    }
    {
        int n = idx >> 9, d = idx & 511;
        const float* src = (n < 512) ? &Wq[(size_t)n * DDIM + d]
                         : (n < 1024) ? &Wk[(size_t)(n - 512) * DDIM + d]
                         : &Wv[(size_t)(n - 1024) * DDIM + d];
        wqkv[idx] = f2bf(*src);
    }
}

// ---------- k1b: conv GEMM, BK=32, ring-4 counted-vmcnt pipeline ----------
__global__ __launch_bounds__(512, 2) void k1b_conv(
    const ushort_t* __restrict__ xbf, const ushort_t* __restrict__ wcat,
    const float* __restrict__ conv_b, ushort_t* __restrict__ ybf, float* __restrict__ rs)
{
    __shared__ alignas(16) ushort_t As[4][128 * 32];   // 32 KB
    __shared__ alignas(16) ushort_t Bs[4][256 * 32];   // 64 KB
    const int t = threadIdx.x;
    const int lane = t & 63, w = t >> 6;
    const int lm = lane & 15, lq = lane >> 4;
    const int wm = w >> 2, wn = w & 3;                 // 2 x 4 waves, 64x64 tile each
    const int s0 = blockIdx.x * 128;
    const int n0 = blockIdx.y * 256;
    const int b  = blockIdx.z;
    const ushort_t* Ag = xbf + (size_t)b * SSG * DDIM;   // guard base: g-row = true + 1
    const ushort_t* Bg = wcat + (size_t)n0 * KC;

    // staging thread map
    const int rA  = w * 16 + (lane >> 2), pA = lane & 3;
    const int rB0 = w * 32 + (lane >> 2), rB1 = rB0 + 16;
    const ushort_t* pa0 = Ag + (size_t)(s0 + rA) * DDIM + (pA ^ gsw(rA)) * 8;
    const ushort_t* pb0 = Bg + (size_t)rB0 * KC + (pA ^ gsw(rB0)) * 8;
    const ushort_t* pb1 = Bg + (size_t)rB1 * KC + (pA ^ gsw(rB1)) * 8;
    const int la0 = w * 512, lb0 = w * 1024, lb1 = w * 1024 + 512;

    // read-side frag offsets (elements, within slab)
    int oA[4], oB[4];
    #pragma unroll
    for (int mt = 0; mt < 4; mt++) {
        int ra = wm * 64 + mt * 16 + lm;
        oA[mt] = ra * 32 + (lq ^ gsw(ra)) * 8;
    }
    #pragma unroll
    for (int nt = 0; nt < 4; nt++) {
        int rb = wn * 64 + nt * 16 + lm;
        oB[nt] = rb * 32 + (lq ^ gsw(rb)) * 8;
    }

    f32x4 acc[4][4];
    #pragma unroll
    for (int i = 0; i < 4; i++)
        #pragma unroll
        for (int j = 0; j < 4; j++) acc[i][j] = (f32x4){0.f, 0.f, 0.f, 0.f};

    // ti in [0,48): tap = ti>>4, k-block = ti&15. A source shifts one row per tap.
    #define STG1B(tn, slab) do { \
        int koA = (((tn) >> 4) << 9) + (((tn) & 15) << 5); \
        int koB = (tn) << 5; \
        gload16(pa0 + koA, &As[slab][la0]); \
        gload16(pb0 + koB, &Bs[slab][lb0]); \
        gload16(pb1 + koB, &Bs[slab][lb1]); } while (0)

    STG1B(0, 0); STG1B(1, 1); STG1B(2, 2);
    const int NT = 48;
    for (int ti = 0; ti < NT; ++ti) {
        const int rc = ti & 3;
        if (ti + 3 < NT) STG1B(ti + 3, (ti + 3) & 3);
        PIPE_HEAD_SEL(ti, NT);
        const ushort_t* Acur = &As[rc][0];
        const ushort_t* Bcur = &Bs[rc][0];
        short8 av[4], bv[4];
        #pragma unroll
        for (int mt = 0; mt < 4; mt++) av[mt] = *reinterpret_cast<const short8*>(&Acur[oA[mt]]);
        #pragma unroll
        for (int nt = 0; nt < 4; nt++) bv[nt] = *reinterpret_cast<const short8*>(&Bcur[oB[nt]]);
        MFMA16();
        PIPE_TAIL();
    }
    #undef STG1B

    const int rbase = s0 + wm * 64;
    const int cbase = n0 + wn * 64;
    ushort_t* yb = ybf + (size_t)b * SS * DDIM;
    float* rsb = rs + (size_t)b * SS;
    float bias[4];
    #pragma unroll
    for (int nt = 0; nt < 4; nt++) bias[nt] = conv_b[cbase + nt * 16 + lm];
    #pragma unroll
    for (int mt = 0; mt < 4; mt++) {
        float pr[4] = {0.f, 0.f, 0.f, 0.f};
        #pragma unroll
        for (int nt = 0; nt < 4; nt++) {
            #pragma unroll
            for (int r = 0; r < 4; r++) {
                float val = acc[mt][nt][r] + bias[nt];
                yb[(size_t)(rbase + mt * 16 + lq * 4 + r) * DDIM + cbase + nt * 16 + lm] = f2bf(val);
                pr[r] = fmaf(val, val, pr[r]);
            }
        }
        #pragma unroll
        for (int r = 0; r < 4; r++) {
            float p = pr[r];
            p += __shfl_xor(p, 1, 64); p += __shfl_xor(p, 2, 64);
            p += __shfl_xor(p, 4, 64); p += __shfl_xor(p, 8, 64);
            if (lm == 0) atomicAdd(&rsb[rbase + mt * 16 + lq * 4 + r], p);
        }
    }
}

// ---------- k1n: x_norm ----------
__global__ __launch_bounds__(256) void k1n_norm(
    const ushort_t* __restrict__ ybf, const float* __restrict__ rs,
    const float* __restrict__ pre_g, ushort_t* __restrict__ xnbf)
{
    const int t = threadIdx.x;
    const int b = blockIdx.y;
    const int r0 = blockIdx.x * 8;
    float2 pg = *reinterpret_cast<const float2*>(&pre_g[2 * t]);
    for (int r = 0; r < 8; r++) {
        size_t row = (size_t)b * SS + r0 + r;
        float inv = rsqrtf(rs[row] * (1.0f / DDIM) + EPSV);
        unsigned int yv = *reinterpret_cast<const unsigned int*>(&ybf[row * DDIM + 2 * t]);
        float v0 = bf2f((ushort_t)(yv & 0xFFFF)), v1 = bf2f((ushort_t)(yv >> 16));
        *reinterpret_cast<unsigned int*>(&xnbf[row * DDIM + 2 * t]) =
            packbf(v0 * inv * pg.x, v1 * inv * pg.y);
    }
}

// ---------- k1c: QKV GEMM, BK=32, ring-4 counted-vmcnt pipeline ----------
__global__ __launch_bounds__(512, 2) void k1c_qkv(
    const ushort_t* __restrict__ xnbf, const ushort_t* __restrict__ wqkv,
    ushort_t* __restrict__ qraw, ushort_t* __restrict__ kraw, ushort_t* __restrict__ vb,
    float* __restrict__ rq, float* __restrict__ rk)
{
    __shared__ alignas(16) ushort_t As[4][128 * 32];
    __shared__ alignas(16) ushort_t Bs[4][256 * 32];
    const int t = threadIdx.x;
    const int lane = t & 63, w = t >> 6;
    const int lm = lane & 15, lq = lane >> 4;
    const int wm = w >> 2, wn = w & 3;
    const int s0 = blockIdx.x * 128;
    const int n0 = blockIdx.y * 256;
    const int b  = blockIdx.z;
    const ushort_t* Ag = xnbf + ((size_t)b * SS + s0) * DDIM;
    const ushort_t* Bg = wqkv + (size_t)n0 * DDIM;

    const int rA  = w * 16 + (lane >> 2), pA = lane & 3;
    const int rB0 = w * 32 + (lane >> 2), rB1 = rB0 + 16;
    const ushort_t* pa0 = Ag + (size_t)rA * DDIM + (pA ^ gsw(rA)) * 8;
    const ushort_t* pb0 = Bg + (size_t)rB0 * DDIM + (pA ^ gsw(rB0)) * 8;
    const ushort_t* pb1 = Bg + (size_t)rB1 * DDIM + (pA ^ gsw(rB1)) * 8;
    const int la0 = w * 512, lb0 = w * 1024, lb1 = w * 1024 + 512;

    int oA[4], oB[4];
    #pragma unroll
    for (int mt = 0; mt < 4; mt++) {
        int ra = wm * 64 + mt * 16 + lm;
        oA[mt] = ra * 32 + (lq ^ gsw(ra)) * 8;
    }
    #pragma unroll
    for (int nt = 0; nt < 4; nt++) {
        int rb = wn * 64 + nt * 16 + lm;
        oB[nt] = rb * 32 + (lq ^ gsw(rb)) * 8;
    }

    f32x4 acc[4][4];
    #pragma unroll
    for (int i = 0; i < 4; i++)
        #pragma unroll
        for (int j = 0; j < 4; j++) acc[i][j] = (f32x4){0.f, 0.f, 0.f, 0.f};

    #define STG1C(tn, slab) do { \
        int ko = (tn) << 5; \
        gload16(pa0 + ko, &As[slab][la0]); \
        gload16(pb0 + ko, &Bs[slab][lb0]); \
        gload16(pb1 + ko, &Bs[slab][lb1]); } while (0)

    STG1C(0, 0); STG1C(1, 1); STG1C(2, 2);
    const int NT = 16;
    for (int ti = 0; ti < NT; ++ti) {
        const int rc = ti & 3;
        if (ti + 3 < NT) STG1C(ti + 3, (ti + 3) & 3);
        PIPE_HEAD_SEL(ti, NT);
        const ushort_t* Acur = &As[rc][0];
        const ushort_t* Bcur = &Bs[rc][0];
        short8 av[4], bv[4];
        #pragma unroll
        for (int mt = 0; mt < 4; mt++) av[mt] = *reinterpret_cast<const short8*>(&Acur[oA[mt]]);
        #pragma unroll
        for (int nt = 0; nt < 4; nt++) bv[nt] = *reinterpret_cast<const short8*>(&Bcur[oB[nt]]);
        MFMA16();
        PIPE_TAIL();
    }
    #undef STG1C

    const int which = blockIdx.y >> 1;              // y in 0..5 -> 0=q 1=k 2=v
    const int rbase = s0 + wm * 64;
    const int cbase = (blockIdx.y & 1) * 256 + wn * 64;
    if (which == 2) {
        ushort_t* vbb = vb + (size_t)b * SS * DDIM;
        #pragma unroll
        for (int mt = 0; mt < 4; mt++)
            #pragma unroll
            for (int nt = 0; nt < 4; nt++)
                #pragma unroll
                for (int r = 0; r < 4; r++)
                    vbb[(size_t)(rbase + mt * 16 + lq * 4 + r) * DDIM + cbase + nt * 16 + lm] =
                        f2bf(acc[mt][nt][r]);
    } else {
        ushort_t* db2 = (which ? kraw : qraw) + (size_t)b * SS * DDIM;
        float* rb = (which ? rk : rq) + (size_t)b * SS;
        #pragma unroll
        for (int mt = 0; mt < 4; mt++) {
            float pr[4] = {0.f, 0.f, 0.f, 0.f};
            #pragma unroll
            for (int nt = 0; nt < 4; nt++) {
                #pragma unroll
                for (int r = 0; r < 4; r++) {
                    float val = acc[mt][nt][r];
                    db2[(size_t)(rbase + mt * 16 + lq * 4 + r) * DDIM + cbase + nt * 16 + lm] = f2bf(val);
                    pr[r] = fmaf(val, val, pr[r]);
                }
            }
            #pragma unroll
            for (int r = 0; r < 4; r++) {
                float p = pr[r];
                p += __shfl_xor(p, 1, 64); p += __shfl_xor(p, 2, 64);
                p += __shfl_xor(p, 4, 64); p += __shfl_xor(p, 8, 64);
                if (lm == 0) atomicAdd(&rb[rbase + mt * 16 + lq * 4 + r], p);
            }
        }
    }
}

// ---------- k1d: rmsnorm(q,k) + rope, in-place ----------
__global__ __launch_bounds__(256) void k1d_rope(
    ushort_t* q_io, ushort_t* k_io,
    const float* __restrict__ rq, const float* __restrict__ rk,
    const float* __restrict__ q_g, const float* __restrict__ k_g)
{
    const int t = threadIdx.x;
    const int b = blockIdx.y;
    const int r0 = blockIdx.x * 8;
    const int c0 = 2 * t;
    float qg0 = q_g[c0], qg1 = q_g[c0 + 1];
    float kg0 = k_g[c0], kg1 = k_g[c0 + 1];
    float invf = (float)pow(10000.0, -(double)c0 / (double)DDIM);
    for (int r = 0; r < 8; r++) {
        int srow = r0 + r;
        size_t rowi = (size_t)b * SS + srow;
        float iq = rsqrtf(rq[rowi] * (1.0f / DDIM) + EPSV);
        float ik = rsqrtf(rk[rowi] * (1.0f / DDIM) + EPSV);
        size_t off = rowi * DDIM + c0;
        unsigned int qv = *reinterpret_cast<const unsigned int*>(&q_io[off]);
        unsigned int kv = *reinterpret_cast<const unsigned int*>(&k_io[off]);
        float q0 = bf2f((ushort_t)(qv & 0xFFFF)) * iq * qg0;
        float q1 = bf2f((ushort_t)(qv >> 16)) * iq * qg1;
        float k0v = bf2f((ushort_t)(kv & 0xFFFF)) * ik * kg0;
        float k1v = bf2f((ushort_t)(kv >> 16)) * ik * kg1;
        float ang = (float)srow * invf, sn, cs;
        sincosf(ang, &sn, &cs);
        *reinterpret_cast<unsigned int*>(&q_io[off]) = packbf(q0 * cs - q1 * sn, q0 * sn + q1 * cs);
        *reinterpret_cast<unsigned int*>(&k_io[off]) = packbf(k0v * cs - k1v * sn, k0v * sn + k1v * cs);
    }
}

// ---------- k2a: scores GEMM, BK=32, ring-4 counted-vmcnt pipeline -> P + row sums l ----------
// Grid (BB, qt, kt): linear id % 8 == batch -> XCD-affine; per-batch Q+K fits L2.
__global__ __launch_bounds__(512, 2) void k2a_rowsum(
    const ushort_t* __restrict__ qb, const ushort_t* __restrict__ kb,
    ushort_t* __restrict__ P, float* __restrict__ l)
{
    __shared__ alignas(16) ushort_t As[4][128 * 32];
    __shared__ alignas(16) ushort_t Bs[4][256 * 32];
    const int t = threadIdx.x;
    const int lane = t & 63, w = t >> 6;
    const int lm = lane & 15, lq = lane >> 4;
    const int wm = w >> 2, wn = w & 3;
    const int b   = blockIdx.x;
    const int qt  = blockIdx.y;     // 16 q-tiles of 128
    const int ktb = blockIdx.z;     // 8  k-tiles of 256
    const ushort_t* Ag = qb + ((size_t)b * SS + qt * 128) * DDIM;
    const ushort_t* Bg = kb + ((size_t)b * SS + ktb * 256) * DDIM;

    const int rA  = w * 16 + (lane >> 2), pA = lane & 3;
    const int rB0 = w * 32 + (lane >> 2), rB1 = rB0 + 16;
    const ushort_t* pa0 = Ag + (size_t)rA * DDIM + (pA ^ gsw(rA)) * 8;
    const ushort_t* pb0 = Bg + (size_t)rB0 * DDIM + (pA ^ gsw(rB0)) * 8;
    const ushort_t* pb1 = Bg + (size_t)rB1 * DDIM + (pA ^ gsw(rB1)) * 8;
    const int la0 = w * 512, lb0 = w * 1024, lb1 = w * 1024 + 512;

    int oA[4], oB[4];
    #pragma unroll
    for (int mt = 0; mt < 4; mt++) {
        int ra = wm * 64 + mt * 16 + lm;
        oA[mt] = ra * 32 + (lq ^ gsw(ra)) * 8;
    }
    #pragma unroll
    for (int nt = 0; nt < 4; nt++) {
        int rb = wn * 64 + nt * 16 + lm;
        oB[nt] = rb * 32 + (lq ^ gsw(rb)) * 8;
    }

    f32x4 acc[4][4];
    #pragma unroll
    for (int i = 0; i < 4; i++)
        #pragma unroll
        for (int j = 0; j < 4; j++) acc[i][j] = (f32x4){0.f, 0.f, 0.f, 0.f};

    #define STG2A(tn, slab) do { \
        int ko = (tn) << 5; \
        gload16(pa0 + ko, &As[slab][la0]); \
        gload16(pb0 + ko, &Bs[slab][lb0]); \
        gload16(pb1 + ko, &Bs[slab][lb1]); } while (0)

    STG2A(0, 0); STG2A(1, 1); STG2A(2, 2);
    const int NT = 16;
    for (int ti = 0; ti < NT; ++ti) {
        const int rc = ti & 3;
        if (ti + 3 < NT) STG2A(ti + 3, (ti + 3) & 3);
        PIPE_HEAD_SEL(ti, NT);
        const ushort_t* Acur = &As[rc][0];
        const ushort_t* Bcur = &Bs[rc][0];
        short8 av[4], bv[4];
        #pragma unroll
        for (int mt = 0; mt < 4; mt++) av[mt] = *reinterpret_cast<const short8*>(&Acur[oA[mt]]);
        #pragma unroll
        for (int nt = 0; nt < 4; nt++) bv[nt] = *reinterpret_cast<const short8*>(&Bcur[oB[nt]]);
        MFMA16();
        PIPE_TAIL();
    }
    #undef STG2A

    const int rbase = qt * 128 + wm * 64;
    const int cbase = ktb * 256 + wn * 64;
    ushort_t* Pb = P + (size_t)b * SS * SS;
    float* lrow = l + (size_t)b * SS;
    #pragma unroll
    for (int mt = 0; mt < 4; mt++) {
        #pragma unroll
        for (int r = 0; r < 4; r++) {
            const int row = rbase + mt * 16 + lq * 4 + r;
            float rowp = 0.f;
            #pragma unroll
            for (int nt = 0; nt < 4; nt++) {
                float e = __expf(acc[mt][nt][r] * SCALE);
                Pb[(size_t)row * SS + cbase + nt * 16 + lm] = f2bf(e);
                rowp += e;
            }
            float p = rowp;
            p += __shfl_xor(p, 1, 64); p += __shfl_xor(p, 2, 64);
            p += __shfl_xor(p, 4, 64); p += __shfl_xor(p, 8, 64);
            if (lm == 0) atomicAdd(&lrow[row], p);
        }
    }
}

// ---------- k2c: cw[k] = sum_q P[q][k] / l[q] ----------
__global__ __launch_bounds__(256) void k2c_colred(
    const ushort_t* __restrict__ P, const float* __restrict__ l,
    float* __restrict__ cw)
{
    const int t = threadIdx.x;
    const int b = blockIdx.z;
    const int k0 = blockIdx.x * 1024 + t * 4;
    const int q0 = blockIdx.y * 128;
    const ushort_t* Pb = P + ((size_t)b * SS + q0) * SS;
    const float* lb = l + (size_t)b * SS + q0;
    float a0 = 0.f, a1 = 0.f, a2 = 0.f, a3 = 0.f;
    for (int q = 0; q < 128; q++) {
        float rl = 1.0f / lb[q];
        uint2 pp = *reinterpret_cast<const uint2*>(&Pb[(size_t)q * SS + k0]);
        a0 = fmaf(bf2f((ushort_t)(pp.x & 0xFFFF)), rl, a0);
        a1 = fmaf(bf2f((ushort_t)(pp.x >> 16)), rl, a1);
        a2 = fmaf(bf2f((ushort_t)(pp.y & 0xFFFF)), rl, a2);
        a3 = fmaf(bf2f((ushort_t)(pp.y >> 16)), rl, a3);
    }
    atomicAdd(&cw[(size_t)b * SS + k0], a0);
    atomicAdd(&cw[(size_t)b * SS + k0 + 1], a1);
    atomicAdd(&cw[(size_t)b * SS + k0 + 2], a2);
    atomicAdd(&cw[(size_t)b * SS + k0 + 3], a3);
}

// ---------- k4: out = (xsum + sum_k cw*v) / S ----------
__global__ __launch_bounds__(256) void k4_out(
    const float* __restrict__ xsum, const ushort_t* __restrict__ v,
    const float* __restrict__ cwv, float* __restrict__ out)
{
    const int b = blockIdx.x, c = blockIdx.y;
    const int t = threadIdx.x;
    const int srow0 = c * (SS / 16);
    const ushort_t* vb = v + ((size_t)b * SS + srow0) * DDIM;
    const float* cwb   = cwv + (size_t)b * SS + srow0;
    float a0 = (c == 0) ? xsum[b * DDIM + t]       : 0.f;
    float a1 = (c == 0) ? xsum[b * DDIM + t + 256] : 0.f;
    for (int r = 0; r < SS / 16; r++) {
        float w = cwb[r];
        a0 += w * bf2f(vb[(size_t)r * DDIM + t]);
        a1 += w * bf2f(vb[(size_t)r * DDIM + t + 256]);
    }
    atomicAdd(&out[b * DDIM + t],       a0 * (1.0f / SS));
    atomicAdd(&out[b * DDIM + t + 256], a1 * (1.0f / SS));
}

extern "C" void kernel_launch(void* const* d_in, const int* in_sizes, int n_in,
                              void* d_out, int out_size, void* d_ws, size_t ws_size,
                              hipStream_t stream)
{
    const float* x      = (const float*)d_in[0];
    const float* conv_w = (const float*)d_in[1];
    const float* conv_b = (const float*)d_in[2];
    const float* pre_g  = (const float*)d_in[3];
    const float* q_g    = (const float*)d_in[4];
    const float* k_g    = (const float*)d_in[5];
    const float* Wq     = (const float*)d_in[6];
    const float* Wk     = (const float*)d_in[7];
    const float* Wv     = (const float*)d_in[8];
    float* out          = (float*)d_out;

    const size_t NTOK  = (size_t)BB * SS * DDIM;
    const size_t NTOKG = (size_t)BB * SSG * DDIM;
    char* p = (char*)d_ws;
    ushort_t* xbf = (ushort_t*)p; p += NTOKG * 2;
    ushort_t* ybf = (ushort_t*)p; p += NTOK * 2;
    ushort_t* xn  = (ushort_t*)p; p += NTOK * 2;
    /* pad */                     p += NTOK * 2;
    ushort_t* qio = (ushort_t*)p; p += NTOK * 2;
    ushort_t* kio = (ushort_t*)p; p += NTOK * 2;
    ushort_t* vb  = (ushort_t*)p; p += NTOK * 2;
    ushort_t* wcat = (ushort_t*)p; p += (size_t)DDIM * KC * 2;
    ushort_t* wqkv = (ushort_t*)p; p += (size_t)KC * DDIM * 2;
    float* rs   = (float*)p; p += (size_t)BB * SS * 4;
    float* rq   = (float*)p; p += (size_t)BB * SS * 4;
    float* rk   = (float*)p; p += (size_t)BB * SS * 4;
    float* lbuf = (float*)p; p += (size_t)BB * SS * 4;
    float* cwb  = (float*)p; p += (size_t)BB * SS * 4;
    float* xsum = (float*)p; p += (size_t)BB * DDIM * 4;

    ushort_t* Pbuf = xbf;   // 67.1 MB aliased region (xbf/ybf/xn/pad dead by k2a)

    (void)hipMemsetAsync(d_out, 0, (size_t)out_size * sizeof(float), stream);
    (void)hipMemsetAsync(rs, 0, ((size_t)BB * SS * 5 + (size_t)BB * DDIM) * sizeof(float), stream);

    kx_cast<<<dim3(SS / 16, BB), 256, 0, stream>>>(x, xbf, xsum);
    k0_prep<<<dim3(DDIM * KC / 256), 256, 0, stream>>>(conv_w, Wq, Wk, Wv, wcat, wqkv);
    k1b_conv<<<dim3(SS / 128, 2, BB), 512, 0, stream>>>(xbf, wcat, conv_b, ybf, rs);
    k1n_norm<<<dim3(SS / 8, BB), 256, 0, stream>>>(ybf, rs, pre_g, xn);
    k1c_qkv<<<dim3(SS / 128, 6, BB), 512, 0, stream>>>(xn, wqkv, qio, kio, vb, rq, rk);
    k1d_rope<<<dim3(SS / 8, BB), 256, 0, stream>>>(qio, kio, rq, rk, q_g, k_g);
    k2a_rowsum<<<dim3(BB, SS / 128, SS / 256), 512, 0, stream>>>(qio, kio, Pbuf, lbuf);
    k2c_colred<<<dim3(SS / 1024, SS / 128, BB), 256, 0, stream>>>(Pbuf, lbuf, cwb);
    k4_out<<<dim3(BB, 16), 256, 0, stream>>>(xsum, vb, cwb, out);
}

// Round 3
// 284.032 us; speedup vs baseline: 1.1475x; 1.1475x over previous
//
#include <hip/hip_runtime.h>
#include <math.h>

#define BB 8
#define SS 2048
#define SSG 2050          // SS + 2 guard rows per batch for conv halo
#define DDIM 512
#define KC 1536
#define EPSV 1e-6f
#define SCALE 0.044194173824159216f   // 1/sqrt(512)

typedef unsigned short ushort_t;
using short8 = __attribute__((ext_vector_type(8))) short;
using f32x4  = __attribute__((ext_vector_type(4))) float;

__device__ inline unsigned short f2bf(float f) {
    union { float f; unsigned int u; } v; v.f = f;
    unsigned int r = v.u + 0x7FFFu + ((v.u >> 16) & 1u);   // RNE
    return (unsigned short)(r >> 16);
}
__device__ inline unsigned int packbf(float a, float b) {
    return (unsigned int)f2bf(a) | ((unsigned int)f2bf(b) << 16);
}
__device__ inline float bf2f(unsigned short s) {
    union { unsigned int u; float f; } v; v.u = ((unsigned int)s) << 16; return v.f;
}

// async global->LDS, 16B/lane; LDS dest is wave-uniform base + lane*16 (linear).
__device__ inline void gload16(const ushort_t* g, ushort_t* l) {
    __builtin_amdgcn_global_load_lds(
        (__attribute__((address_space(1))) const void*)g,
        (__attribute__((address_space(3))) void*)l, 16, 0, 0);
}

// swizzled fragment read from a linear [128][64] bf16 tile (128B rows).
// logical 16B chunk c (0..7) of row -> stored at chunk c ^ (row&7).
// source side applies the same XOR, so LDS stays linear for gload_lds (rule #21).
// R1 measured: SQ_LDS_BANK_CONFLICT == 0 with this pair.
__device__ inline short8 ldswz(const ushort_t* s, int row, int c) {
    return *reinterpret_cast<const short8*>(&s[(row << 6) + ((c ^ (row & 7)) << 3)]);
}

// ---------- kx: x fp32 -> bf16 (guarded layout), plus xsum[b][d] = sum_s x ----------
__global__ __launch_bounds__(256) void kx_cast(const float* __restrict__ x,
                                               ushort_t* __restrict__ xbf,
                                               float* __restrict__ xsum)
{
    const int t = threadIdx.x;
    const int b = blockIdx.y;
    const int r0 = blockIdx.x * 16;
    const int c0 = 2 * t;
    if (blockIdx.x == 0) {   // zero guard rows (row -1 and row SS of this batch)
        *reinterpret_cast<unsigned int*>(&xbf[((size_t)b * SSG) * DDIM + c0]) = 0u;
        *reinterpret_cast<unsigned int*>(&xbf[((size_t)b * SSG + SS + 1) * DDIM + c0]) = 0u;
    }
    float s0 = 0.f, s1 = 0.f;
    for (int r = 0; r < 16; r++) {
        size_t srow = (size_t)b * SS + r0 + r;
        size_t drow = (size_t)b * SSG + 1 + r0 + r;
        float2 v = *reinterpret_cast<const float2*>(&x[srow * DDIM + c0]);
        s0 += v.x; s1 += v.y;
        *reinterpret_cast<unsigned int*>(&xbf[drow * DDIM + c0]) = packbf(v.x, v.y);
    }
    atomicAdd(&xsum[b * DDIM + c0], s0);
    atomicAdd(&xsum[b * DDIM + c0 + 1], s1);
}

// ---------- k0: weights -> bf16 ----------
__global__ __launch_bounds__(256) void k0_prep(
    const float* __restrict__ conv_w, const float* __restrict__ Wq,
    const float* __restrict__ Wk, const float* __restrict__ Wv,
    ushort_t* __restrict__ wcat, ushort_t* __restrict__ wqkv)
{
    int idx = blockIdx.x * 256 + threadIdx.x;   // < 512*1536
    {
        int o = idx / KC, kk = idx - o * KC;
        int t = kk >> 9, i = kk & 511;
        wcat[idx] = f2bf(conv_w[(size_t)o * KC + i * 3 + t]);
    }
    {
        int n = idx >> 9, d = idx & 511;
        const float* src = (n < 512) ? &Wq[(size_t)n * DDIM + d]
                         : (n < 1024) ? &Wk[(size_t)(n - 512) * DDIM + d]
                         : &Wv[(size_t)(n - 1024) * DDIM + d];
        wqkv[idx] = f2bf(*src);
    }
}

// ---------- shared GEMM inner compute (one BK=64 tile from buffer) ----------
#define COMPUTE_TILE(Acur, Bcur) do { \
    _Pragma("unroll") \
    for (int half = 0; half < 2; half++) { \
        const int cb = (half << 2) | lq; \
        short8 af0 = ldswz(Acur, wm * 64 +  0 + lm, cb); \
        short8 af1 = ldswz(Acur, wm * 64 + 16 + lm, cb); \
        short8 af2 = ldswz(Acur, wm * 64 + 32 + lm, cb); \
        short8 af3 = ldswz(Acur, wm * 64 + 48 + lm, cb); \
        _Pragma("unroll") \
        for (int nt = 0; nt < 4; nt++) { \
            short8 bfv = ldswz(Bcur, wn * 64 + nt * 16 + lm, cb); \
            acc[0][nt] = __builtin_amdgcn_mfma_f32_16x16x32_bf16(af0, bfv, acc[0][nt], 0, 0, 0); \
            acc[1][nt] = __builtin_amdgcn_mfma_f32_16x16x32_bf16(af1, bfv, acc[1][nt], 0, 0, 0); \
            acc[2][nt] = __builtin_amdgcn_mfma_f32_16x16x32_bf16(af2, bfv, acc[2][nt], 0, 0, 0); \
            acc[3][nt] = __builtin_amdgcn_mfma_f32_16x16x32_bf16(af3, bfv, acc[3][nt], 0, 0, 0); \
        } \
    } } while (0)

// ---------- k1b: conv GEMM, BK=64, 2-phase double-buffered gload_lds ----------
__global__ __launch_bounds__(256) void k1b_conv(
    const ushort_t* __restrict__ xbf, const ushort_t* __restrict__ wcat,
    const float* __restrict__ conv_b, ushort_t* __restrict__ ybf, float* __restrict__ rs)
{
    __shared__ alignas(16) ushort_t As[2][128 * 64];
    __shared__ alignas(16) ushort_t Bs[2][128 * 64];
    const int t = threadIdx.x;
    const int lane = t & 63, w = t >> 6;
    const int lm = lane & 15, lq = lane >> 4;
    const int wm = w >> 1, wn = w & 1;
    const int lr = lane >> 3;                 // row within 8-row load block
    const int lc = ((lane & 7) ^ lr) << 3;    // source-side XOR-swizzled chunk
    const int s0 = blockIdx.x * 128;
    const int n0 = blockIdx.y * 128;
    const int b  = blockIdx.z;
    const ushort_t* Ag = xbf + (size_t)b * SSG * DDIM;   // guard base: g-row = true + 1
    const ushort_t* Bg = wcat + (size_t)n0 * KC;

    // dc walks (tap, 64-col block): A offset = base + 64*dc (uniform across taps).
    const ushort_t* pa[4]; const ushort_t* pb[4];
    int la[4];
    #pragma unroll
    for (int i = 0; i < 4; i++) {
        const int tr = (w * 4 + i) * 8 + lr;
        pa[i] = &Ag[(size_t)(s0 + tr) * DDIM + lc];
        pb[i] = &Bg[(size_t)tr * KC + lc];
        la[i] = (w * 4 + i) * 512;
    }

    f32x4 acc[4][4];
    #pragma unroll
    for (int i = 0; i < 4; i++)
        #pragma unroll
        for (int j = 0; j < 4; j++) acc[i][j] = (f32x4){0.f, 0.f, 0.f, 0.f};

    #define STG1B(tn, bufi) do { \
        const int koA = (tn) * 64; \
        _Pragma("unroll") \
        for (int i = 0; i < 4; i++) { \
            gload16(pa[i] + koA, &As[bufi][la[i]]); \
            gload16(pb[i] + koA, &Bs[bufi][la[i]]); \
        } } while (0)

    const int NT = 24;
    STG1B(0, 0);
    __syncthreads();                         // drain tile0
    for (int dc = 0; dc < NT; dc++) {
        const int cur = dc & 1;
        if (dc + 1 < NT) STG1B(dc + 1, cur ^ 1);   // issue next tile under compute
        COMPUTE_TILE(&As[cur][0], &Bs[cur][0]);
        __syncthreads();                     // drains vmcnt(0): next tile published
    }
    #undef STG1B

    const int rbase = s0 + wm * 64;
    const int cbase = n0 + wn * 64;
    ushort_t* yb = ybf + (size_t)b * SS * DDIM;
    float* rsb = rs + (size_t)b * SS;
    float bias[4];
    #pragma unroll
    for (int nt = 0; nt < 4; nt++) bias[nt] = conv_b[cbase + nt * 16 + lm];
    #pragma unroll
    for (int mt = 0; mt < 4; mt++) {
        float pr[4] = {0.f, 0.f, 0.f, 0.f};
        #pragma unroll
        for (int nt = 0; nt < 4; nt++) {
            #pragma unroll
            for (int r = 0; r < 4; r++) {
                float val = acc[mt][nt][r] + bias[nt];
                yb[(size_t)(rbase + mt * 16 + lq * 4 + r) * DDIM + cbase + nt * 16 + lm] = f2bf(val);
                pr[r] = fmaf(val, val, pr[r]);
            }
        }
        #pragma unroll
        for (int r = 0; r < 4; r++) {
            float p = pr[r];
            p += __shfl_xor(p, 1, 64); p += __shfl_xor(p, 2, 64);
            p += __shfl_xor(p, 4, 64); p += __shfl_xor(p, 8, 64);
            if (lm == 0) atomicAdd(&rsb[rbase + mt * 16 + lq * 4 + r], p);
        }
    }
}

// ---------- k1n: x_norm ----------
__global__ __launch_bounds__(256) void k1n_norm(
    const ushort_t* __restrict__ ybf, const float* __restrict__ rs,
    const float* __restrict__ pre_g, ushort_t* __restrict__ xnbf)
{
    const int t = threadIdx.x;
    const int b = blockIdx.y;
    const int r0 = blockIdx.x * 8;
    float2 pg = *reinterpret_cast<const float2*>(&pre_g[2 * t]);
    for (int r = 0; r < 8; r++) {
        size_t row = (size_t)b * SS + r0 + r;
        float inv = rsqrtf(rs[row] * (1.0f / DDIM) + EPSV);
        unsigned int yv = *reinterpret_cast<const unsigned int*>(&ybf[row * DDIM + 2 * t]);
        float v0 = bf2f((ushort_t)(yv & 0xFFFF)), v1 = bf2f((ushort_t)(yv >> 16));
        *reinterpret_cast<unsigned int*>(&xnbf[row * DDIM + 2 * t]) =
            packbf(v0 * inv * pg.x, v1 * inv * pg.y);
    }
}

// ---------- k1c: QKV GEMM, BK=64, 2-phase double-buffered gload_lds ----------
__global__ __launch_bounds__(256) void k1c_qkv(
    const ushort_t* __restrict__ xnbf, const ushort_t* __restrict__ wqkv,
    ushort_t* __restrict__ qraw, ushort_t* __restrict__ kraw, ushort_t* __restrict__ vb,
    float* __restrict__ rq, float* __restrict__ rk)
{
    __shared__ alignas(16) ushort_t As[2][128 * 64];
    __shared__ alignas(16) ushort_t Bs[2][128 * 64];
    const int t = threadIdx.x;
    const int lane = t & 63, w = t >> 6;
    const int lm = lane & 15, lq = lane >> 4;
    const int wm = w >> 1, wn = w & 1;
    const int lr = lane >> 3;
    const int lc = ((lane & 7) ^ lr) << 3;
    const int s0 = blockIdx.x * 128;
    const int n0 = blockIdx.y * 128;
    const int b  = blockIdx.z;
    const ushort_t* Ag = xnbf + ((size_t)b * SS + s0) * DDIM;
    const ushort_t* Bg = wqkv + (size_t)n0 * DDIM;

    const ushort_t* pa[4]; const ushort_t* pb[4];
    int la[4];
    #pragma unroll
    for (int i = 0; i < 4; i++) {
        const int tr = (w * 4 + i) * 8 + lr;
        pa[i] = &Ag[(size_t)tr * DDIM + lc];
        pb[i] = &Bg[(size_t)tr * DDIM + lc];
        la[i] = (w * 4 + i) * 512;
    }

    f32x4 acc[4][4];
    #pragma unroll
    for (int i = 0; i < 4; i++)
        #pragma unroll
        for (int j = 0; j < 4; j++) acc[i][j] = (f32x4){0.f, 0.f, 0.f, 0.f};

    #define STG1C(tn, bufi) do { \
        const int ko = (tn) * 64; \
        _Pragma("unroll") \
        for (int i = 0; i < 4; i++) { \
            gload16(pa[i] + ko, &As[bufi][la[i]]); \
            gload16(pb[i] + ko, &Bs[bufi][la[i]]); \
        } } while (0)

    const int NT = 8;
    STG1C(0, 0);
    __syncthreads();
    for (int dc = 0; dc < NT; dc++) {
        const int cur = dc & 1;
        if (dc + 1 < NT) STG1C(dc + 1, cur ^ 1);
        COMPUTE_TILE(&As[cur][0], &Bs[cur][0]);
        __syncthreads();
    }
    #undef STG1C

    const int which = blockIdx.y >> 2;              // 0=q 1=k 2=v
    const int rbase = s0 + wm * 64;
    const int cbase = ((blockIdx.y & 3) * 128) + wn * 64;
    if (which == 2) {
        ushort_t* vbb = vb + (size_t)b * SS * DDIM;
        #pragma unroll
        for (int mt = 0; mt < 4; mt++)
            #pragma unroll
            for (int nt = 0; nt < 4; nt++)
                #pragma unroll
                for (int r = 0; r < 4; r++)
                    vbb[(size_t)(rbase + mt * 16 + lq * 4 + r) * DDIM + cbase + nt * 16 + lm] =
                        f2bf(acc[mt][nt][r]);
    } else {
        ushort_t* db2 = (which ? kraw : qraw) + (size_t)b * SS * DDIM;
        float* rb = (which ? rk : rq) + (size_t)b * SS;
        #pragma unroll
        for (int mt = 0; mt < 4; mt++) {
            float pr[4] = {0.f, 0.f, 0.f, 0.f};
            #pragma unroll
            for (int nt = 0; nt < 4; nt++) {
                #pragma unroll
                for (int r = 0; r < 4; r++) {
                    float val = acc[mt][nt][r];
                    db2[(size_t)(rbase + mt * 16 + lq * 4 + r) * DDIM + cbase + nt * 16 + lm] = f2bf(val);
                    pr[r] = fmaf(val, val, pr[r]);
                }
            }
            #pragma unroll
            for (int r = 0; r < 4; r++) {
                float p = pr[r];
                p += __shfl_xor(p, 1, 64); p += __shfl_xor(p, 2, 64);
                p += __shfl_xor(p, 4, 64); p += __shfl_xor(p, 8, 64);
                if (lm == 0) atomicAdd(&rb[rbase + mt * 16 + lq * 4 + r], p);
            }
        }
    }
}

// ---------- k1d: rmsnorm(q,k) + rope, in-place ----------
__global__ __launch_bounds__(256) void k1d_rope(
    ushort_t* q_io, ushort_t* k_io,
    const float* __restrict__ rq, const float* __restrict__ rk,
    const float* __restrict__ q_g, const float* __restrict__ k_g)
{
    const int t = threadIdx.x;
    const int b = blockIdx.y;
    const int r0 = blockIdx.x * 8;
    const int c0 = 2 * t;
    float qg0 = q_g[c0], qg1 = q_g[c0 + 1];
    float kg0 = k_g[c0], kg1 = k_g[c0 + 1];
    float invf = (float)pow(10000.0, -(double)c0 / (double)DDIM);
    for (int r = 0; r < 8; r++) {
        int srow = r0 + r;
        size_t rowi = (size_t)b * SS + srow;
        float iq = rsqrtf(rq[rowi] * (1.0f / DDIM) + EPSV);
        float ik = rsqrtf(rk[rowi] * (1.0f / DDIM) + EPSV);
        size_t off = rowi * DDIM + c0;
        unsigned int qv = *reinterpret_cast<const unsigned int*>(&q_io[off]);
        unsigned int kv = *reinterpret_cast<const unsigned int*>(&k_io[off]);
        float q0 = bf2f((ushort_t)(qv & 0xFFFF)) * iq * qg0;
        float q1 = bf2f((ushort_t)(qv >> 16)) * iq * qg1;
        float k0v = bf2f((ushort_t)(kv & 0xFFFF)) * ik * kg0;
        float k1v = bf2f((ushort_t)(kv >> 16)) * ik * kg1;
        float ang = (float)srow * invf, sn, cs;
        sincosf(ang, &sn, &cs);
        *reinterpret_cast<unsigned int*>(&q_io[off]) = packbf(q0 * cs - q1 * sn, q0 * sn + q1 * cs);
        *reinterpret_cast<unsigned int*>(&k_io[off]) = packbf(k0v * cs - k1v * sn, k0v * sn + k1v * cs);
    }
}

// ---------- k2a: scores GEMM, BK=64, 2-phase double-buffered -> P + row sums l ----------
// Grid (BB, qt, kt): linear id % 8 == batch -> XCD-affine; per-batch Q+K (4MB) fits one L2.
__global__ __launch_bounds__(256) void k2a_rowsum(
    const ushort_t* __restrict__ qb, const ushort_t* __restrict__ kb,
    ushort_t* __restrict__ P, float* __restrict__ l)
{
    __shared__ alignas(16) ushort_t As[2][128 * 64];
    __shared__ alignas(16) ushort_t Bs[2][128 * 64];
    const int t = threadIdx.x;
    const int lane = t & 63, w = t >> 6;
    const int lm = lane & 15, lq = lane >> 4;
    const int wm = w >> 1, wn = w & 1;
    const int lr = lane >> 3;
    const int lc = ((lane & 7) ^ lr) << 3;
    const int b  = blockIdx.x;
    const int qt = blockIdx.y;
    const int kt = blockIdx.z;
    const ushort_t* Ag = qb + ((size_t)b * SS + qt * 128) * DDIM;
    const ushort_t* Bg = kb + ((size_t)b * SS + kt * 128) * DDIM;

    const ushort_t* pa[4]; const ushort_t* pb[4];
    int la[4];
    #pragma unroll
    for (int i = 0; i < 4; i++) {
        const int tr = (w * 4 + i) * 8 + lr;
        pa[i] = &Ag[(size_t)tr * DDIM + lc];
        pb[i] = &Bg[(size_t)tr * DDIM + lc];
        la[i] = (w * 4 + i) * 512;
    }

    f32x4 acc[4][4];
    #pragma unroll
    for (int i = 0; i < 4; i++)
        #pragma unroll
        for (int j = 0; j < 4; j++) acc[i][j] = (f32x4){0.f, 0.f, 0.f, 0.f};

    #define STG2A(tn, bufi) do { \
        const int ko = (tn) * 64; \
        _Pragma("unroll") \
        for (int i = 0; i < 4; i++) { \
            gload16(pa[i] + ko, &As[bufi][la[i]]); \
            gload16(pb[i] + ko, &Bs[bufi][la[i]]); \
        } } while (0)

    const int NT = 8;
    STG2A(0, 0);
    __syncthreads();
    for (int dc = 0; dc < NT; dc++) {
        const int cur = dc & 1;
        if (dc + 1 < NT) STG2A(dc + 1, cur ^ 1);
        COMPUTE_TILE(&As[cur][0], &Bs[cur][0]);
        __syncthreads();
    }
    #undef STG2A

    const int rbase = qt * 128 + wm * 64;
    const int cbase = kt * 128 + wn * 64;
    ushort_t* Pb = P + (size_t)b * SS * SS;
    float* lrow = l + (size_t)b * SS;
    #pragma unroll
    for (int mt = 0; mt < 4; mt++) {
        #pragma unroll
        for (int r = 0; r < 4; r++) {
            const int row = rbase + mt * 16 + lq * 4 + r;
            float rowp = 0.f;
            #pragma unroll
            for (int nt = 0; nt < 4; nt++) {
                float e = __expf(acc[mt][nt][r] * SCALE);
                Pb[(size_t)row * SS + cbase + nt * 16 + lm] = f2bf(e);
                rowp += e;
            }
            float p = rowp;
            p += __shfl_xor(p, 1, 64); p += __shfl_xor(p, 2, 64);
            p += __shfl_xor(p, 4, 64); p += __shfl_xor(p, 8, 64);
            if (lm == 0) atomicAdd(&lrow[row], p);
        }
    }
}

// ---------- k2c: cw[k] = sum_q P[q][k] / l[q] ----------
__global__ __launch_bounds__(256) void k2c_colred(
    const ushort_t* __restrict__ P, const float* __restrict__ l,
    float* __restrict__ cw)
{
    const int t = threadIdx.x;
    const int b = blockIdx.z;
    const int k0 = blockIdx.x * 1024 + t * 4;
    const int q0 = blockIdx.y * 128;
    const ushort_t* Pb = P + ((size_t)b * SS + q0) * SS;
    const float* lb = l + (size_t)b * SS + q0;
    float a0 = 0.f, a1 = 0.f, a2 = 0.f, a3 = 0.f;
    for (int q = 0; q < 128; q++) {
        float rl = 1.0f / lb[q];
        uint2 pp = *reinterpret_cast<const uint2*>(&Pb[(size_t)q * SS + k0]);
        a0 = fmaf(bf2f((ushort_t)(pp.x & 0xFFFF)), rl, a0);
        a1 = fmaf(bf2f((ushort_t)(pp.x >> 16)), rl, a1);
        a2 = fmaf(bf2f((ushort_t)(pp.y & 0xFFFF)), rl, a2);
        a3 = fmaf(bf2f((ushort_t)(pp.y >> 16)), rl, a3);
    }
    atomicAdd(&cw[(size_t)b * SS + k0], a0);
    atomicAdd(&cw[(size_t)b * SS + k0 + 1], a1);
    atomicAdd(&cw[(size_t)b * SS + k0 + 2], a2);
    atomicAdd(&cw[(size_t)b * SS + k0 + 3], a3);
}

// ---------- k4: out = (xsum + sum_k cw*v) / S ----------
__global__ __launch_bounds__(256) void k4_out(
    const float* __restrict__ xsum, const ushort_t* __restrict__ v,
    const float* __restrict__ cwv, float* __restrict__ out)
{
    const int b = blockIdx.x, c = blockIdx.y;
    const int t = threadIdx.x;
    const int srow0 = c * (SS / 16);
    const ushort_t* vb = v + ((size_t)b * SS + srow0) * DDIM;
    const float* cwb   = cwv + (size_t)b * SS + srow0;
    float a0 = (c == 0) ? xsum[b * DDIM + t]       : 0.f;
    float a1 = (c == 0) ? xsum[b * DDIM + t + 256] : 0.f;
    for (int r = 0; r < SS / 16; r++) {
        float w = cwb[r];
        a0 += w * bf2f(vb[(size_t)r * DDIM + t]);
        a1 += w * bf2f(vb[(size_t)r * DDIM + t + 256]);
    }
    atomicAdd(&out[b * DDIM + t],       a0 * (1.0f / SS));
    atomicAdd(&out[b * DDIM + t + 256], a1 * (1.0f / SS));
}

extern "C" void kernel_launch(void* const* d_in, const int* in_sizes, int n_in,
                              void* d_out, int out_size, void* d_ws, size_t ws_size,
                              hipStream_t stream)
{
    const float* x      = (const float*)d_in[0];
    const float* conv_w = (const float*)d_in[1];
    const float* conv_b = (const float*)d_in[2];
    const float* pre_g  = (const float*)d_in[3];
    const float* q_g    = (const float*)d_in[4];
    const float* k_g    = (const float*)d_in[5];
    const float* Wq     = (const float*)d_in[6];
    const float* Wk     = (const float*)d_in[7];
    const float* Wv     = (const float*)d_in[8];
    float* out          = (float*)d_out;

    const size_t NTOK  = (size_t)BB * SS * DDIM;
    const size_t NTOKG = (size_t)BB * SSG * DDIM;
    char* p = (char*)d_ws;
    ushort_t* xbf = (ushort_t*)p; p += NTOKG * 2;
    ushort_t* ybf = (ushort_t*)p; p += NTOK * 2;
    ushort_t* xn  = (ushort_t*)p; p += NTOK * 2;
    /* pad */                     p += NTOK * 2;
    ushort_t* qio = (ushort_t*)p; p += NTOK * 2;
    ushort_t* kio = (ushort_t*)p; p += NTOK * 2;
    ushort_t* vb  = (ushort_t*)p; p += NTOK * 2;
    ushort_t* wcat = (ushort_t*)p; p += (size_t)DDIM * KC * 2;
    ushort_t* wqkv = (ushort_t*)p; p += (size_t)KC * DDIM * 2;
    float* rs   = (float*)p; p += (size_t)BB * SS * 4;
    float* rq   = (float*)p; p += (size_t)BB * SS * 4;
    float* rk   = (float*)p; p += (size_t)BB * SS * 4;
    float* lbuf = (float*)p; p += (size_t)BB * SS * 4;
    float* cwb  = (float*)p; p += (size_t)BB * SS * 4;
    float* xsum = (float*)p; p += (size_t)BB * DDIM * 4;

    ushort_t* Pbuf = xbf;   // 67.1 MB aliased region (xbf/ybf/xn/pad dead by k2a)

    (void)hipMemsetAsync(d_out, 0, (size_t)out_size * sizeof(float), stream);
    (void)hipMemsetAsync(rs, 0, ((size_t)BB * SS * 5 + (size_t)BB * DDIM) * sizeof(float), stream);

    kx_cast<<<dim3(SS / 16, BB), 256, 0, stream>>>(x, xbf, xsum);
    k0_prep<<<dim3(DDIM * KC / 256), 256, 0, stream>>>(conv_w, Wq, Wk, Wv, wcat, wqkv);
    k1b_conv<<<dim3(SS / 128, 4, BB), 256, 0, stream>>>(xbf, wcat, conv_b, ybf, rs);
    k1n_norm<<<dim3(SS / 8, BB), 256, 0, stream>>>(ybf, rs, pre_g, xn);
    k1c_qkv<<<dim3(SS / 128, 12, BB), 256, 0, stream>>>(xn, wqkv, qio, kio, vb, rq, rk);
    k1d_rope<<<dim3(SS / 8, BB), 256, 0, stream>>>(qio, kio, rq, rk, q_g, k_g);
    k2a_rowsum<<<dim3(BB, SS / 128, SS / 128), 256, 0, stream>>>(qio, kio, Pbuf, lbuf);
    k2c_colred<<<dim3(SS / 1024, SS / 128, BB), 256, 0, stream>>>(Pbuf, lbuf, cwb);
    k4_out<<<dim3(BB, 16), 256, 0, stream>>>(xsum, vb, cwb, out);
}